// Round 10
// baseline (121.415 us; speedup 1.0000x reference)
//
#include <hip/hip_runtime.h>
#include <cstddef>
#include <cstdint>

#define NPT 16384   // N
#define NB  4       // B
// C = 64, K = 16, O = 128

#define T_TILES  4
#define GRID_ATT ((NB * NPT / 4) / T_TILES)   // 4096 blocks, 4 tiles each

typedef float    f32x4 __attribute__((ext_vector_type(4)));
typedef uint32_t u32x4 __attribute__((ext_vector_type(4)));
typedef uint16_t u16x4 __attribute__((ext_vector_type(4)));

__device__ __forceinline__ uint32_t bf16_rtne(float f) {
    uint32_t u = __builtin_bit_cast(uint32_t, f);
    return (u + 0x7FFFu + ((u >> 16) & 1u)) >> 16;
}
__device__ __forceinline__ float bf16_hi(uint32_t w) {   // high 16 bits
    return __builtin_bit_cast(float, w & 0xFFFF0000u);
}
__device__ __forceinline__ float bf16_lo(uint32_t w) {   // low 16 bits
    return __builtin_bit_cast(float, w << 16);
}

// ---------------------------------------------------------------------------
// K1: fused 1x1 conv + BN(eps=1e-5) + ReLU for q, k, v.  (unchanged from r9)
// q out: [B][N][64] bf16 (u16). k,v out PACKED bf16: kv[p][c]=(k<<16)|v (u32).
// ---------------------------------------------------------------------------
__global__ __launch_bounds__(256) void k_qkv(
    const float* __restrict__ feat_in,
    const float* __restrict__ Wq, const float* __restrict__ Wk, const float* __restrict__ Wv,
    const float* __restrict__ Qg, const float* __restrict__ Qb, const float* __restrict__ Qm, const float* __restrict__ Qv,
    const float* __restrict__ Kg, const float* __restrict__ Kb, const float* __restrict__ Km, const float* __restrict__ Kv,
    const float* __restrict__ Vg, const float* __restrict__ Vb, const float* __restrict__ Vm, const float* __restrict__ Vv,
    uint16_t* __restrict__ qo, uint32_t* __restrict__ kvo)
{
    __shared__ float wt[64][192];
    __shared__ float fs[64][64];
    const int tid = threadIdx.x;
    const int b   = blockIdx.y;
    const int n0  = blockIdx.x * 64;

    {
        const int o  = tid >> 2;
        const int cb = (tid & 3) * 16;
        const float* Ws[3] = {Wq, Wk, Wv};
        #pragma unroll
        for (int t = 0; t < 3; ++t) {
            const float4* src = reinterpret_cast<const float4*>(Ws[t] + o * 64 + cb);
            #pragma unroll
            for (int k4 = 0; k4 < 4; ++k4) {
                float4 w4 = src[k4];
                wt[cb + k4 * 4 + 0][t * 64 + o] = w4.x;
                wt[cb + k4 * 4 + 1][t * 64 + o] = w4.y;
                wt[cb + k4 * 4 + 2][t * 64 + o] = w4.z;
                wt[cb + k4 * 4 + 3][t * 64 + o] = w4.w;
            }
        }
    }
    #pragma unroll
    for (int i = 0; i < 16; ++i) {
        int flat = tid + i * 256;
        int c = flat >> 6, n = flat & 63;
        fs[c][n] = feat_in[((size_t)b * 64 + c) * NPT + n0 + n];
    }
    __syncthreads();

    const int to = tid & 15;
    const int tn = tid >> 4;
    float acc[3][4][4];
    #pragma unroll
    for (int t = 0; t < 3; ++t)
        #pragma unroll
        for (int i = 0; i < 4; ++i)
            #pragma unroll
            for (int j = 0; j < 4; ++j) acc[t][i][j] = 0.f;

    #pragma unroll 4
    for (int c = 0; c < 64; ++c) {
        float4 f4  = *reinterpret_cast<const float4*>(&fs[c][tn * 4]);
        float4 wq4 = *reinterpret_cast<const float4*>(&wt[c][to * 4]);
        float4 wk4 = *reinterpret_cast<const float4*>(&wt[c][64 + to * 4]);
        float4 wv4 = *reinterpret_cast<const float4*>(&wt[c][128 + to * 4]);
        float fr[4]    = {f4.x, f4.y, f4.z, f4.w};
        float wr[3][4] = {{wq4.x, wq4.y, wq4.z, wq4.w},
                          {wk4.x, wk4.y, wk4.z, wk4.w},
                          {wv4.x, wv4.y, wv4.z, wv4.w}};
        #pragma unroll
        for (int t = 0; t < 3; ++t)
            #pragma unroll
            for (int oi = 0; oi < 4; ++oi)
                #pragma unroll
                for (int nn = 0; nn < 4; ++nn)
                    acc[t][oi][nn] = fmaf(wr[t][oi], fr[nn], acc[t][oi][nn]);
    }

    float scq[4], shq[4], sck[4], shk[4], scv[4], shv[4];
    #pragma unroll
    for (int oi = 0; oi < 4; ++oi) {
        int o = to * 4 + oi;
        float s;
        s = Qg[o] * rsqrtf(Qv[o] + 1e-5f); scq[oi] = s; shq[oi] = Qb[o] - Qm[o] * s;
        s = Kg[o] * rsqrtf(Kv[o] + 1e-5f); sck[oi] = s; shk[oi] = Kb[o] - Km[o] * s;
        s = Vg[o] * rsqrtf(Vv[o] + 1e-5f); scv[oi] = s; shv[oi] = Vb[o] - Vm[o] * s;
    }
    #pragma unroll
    for (int nn = 0; nn < 4; ++nn) {
        const size_t pidx = (size_t)b * NPT + n0 + tn * 4 + nn;
        u16x4 rq;
        u32x4 pk;
        #pragma unroll
        for (int oi = 0; oi < 4; ++oi) {
            float q  = fmaxf(fmaf(acc[0][oi][nn], scq[oi], shq[oi]), 0.f);
            float rk = fmaxf(fmaf(acc[1][oi][nn], sck[oi], shk[oi]), 0.f);
            float rv = fmaxf(fmaf(acc[2][oi][nn], scv[oi], shv[oi]), 0.f);
            rq[oi] = (uint16_t)bf16_rtne(q);
            pk[oi] = (bf16_rtne(rk) << 16) | bf16_rtne(rv);
        }
        *reinterpret_cast<u16x4*>(qo  + (pidx << 6) + to * 4) = rq;
        *reinterpret_cast<u32x4*>(kvo + (pidx << 6) + to * 4) = pk;
    }
}

// ---------------------------------------------------------------------------
// K2: PIPELINED gather+attention. Each block processes T_TILES=4 tiles of
// 4 points. Per iteration: ISSUE tile t+1's loads (x first, then idx->gathers,
// then q) -> COMPUTE tile t from regs + xs[cur] -> ds_write tile t+1's x
// (counted vmcnt: only x waited, gathers/q stay in flight) -> raw s_barrier
// with lgkmcnt(0) only (NOT __syncthreads: no vmcnt(0) drain). Breaks the
// per-wave serial idx->gather->x chain that TLP alone couldn't hide.
// Double-buffered xs: 34.8 KiB -> 4 blocks/CU (16 waves), same as r5-best.
// Race audit: write buf (cur^1) != read buf (cur); iter t-1 finished reading
// cur^1 before the barrier that admitted waves into iter t. In-place q->feat
// stays safe: each point read+written only by its owner wave.
// ---------------------------------------------------------------------------
__global__ __launch_bounds__(256) void k_attn(
    const float*    __restrict__ xinfo,
    const int*      __restrict__ nidx,
    uint16_t*                    qfeat,   // q in (bf16), feat out (bf16)
    const uint32_t* __restrict__ kv)
{
    __shared__ float xs[2][64][68];
    const int tid  = threadIdx.x;
    const int lane = tid & 63;
    const int wv   = tid >> 6;

    uint32_t gr[16];   // current tile's gathers
    float    qc;
    f32x4    xr[4];    // next tile's x stream (registers)

    // ---------------- prologue: tile 0 ----------------
    {
        const int p0 = blockIdx.x * 4;
        const int b = p0 >> 14, n0 = p0 & 16383, p = p0 + wv;
        // x first (longest latency)
        const float* xbase = xinfo + (((size_t)b * 64) * NPT + n0) * 16;
        #pragma unroll
        for (int i = 0; i < 4; ++i) {
            int f = tid + i * 256, c = f >> 4, s = f & 15;
            xr[i] = __builtin_nontemporal_load(
                reinterpret_cast<const f32x4*>(xbase + (size_t)c * (NPT * 16) + s * 4));
        }
        const int pu = __builtin_amdgcn_readfirstlane(p);
        const int4* ir = reinterpret_cast<const int4*>(nidx + ((size_t)pu << 4));
        int4 a0 = ir[0], a1 = ir[1], a2 = ir[2], a3 = ir[3];
        const int idxs[16] = {a0.x,a0.y,a0.z,a0.w, a1.x,a1.y,a1.z,a1.w,
                              a2.x,a2.y,a2.z,a2.w, a3.x,a3.y,a3.z,a3.w};
        #pragma unroll
        for (int j = 0; j < 16; ++j)
            gr[j] = kv[(((size_t)((b << 14) | idxs[j])) << 6) + lane];
        qc = bf16_lo((uint32_t)__builtin_nontemporal_load(
                 qfeat + ((size_t)p << 6) + lane));
        #pragma unroll
        for (int i = 0; i < 4; ++i) {
            int f = tid + i * 256, c = f >> 4, s = f & 15;
            *reinterpret_cast<f32x4*>(&xs[0][c][s * 4]) = xr[i];
        }
    }
    asm volatile("s_waitcnt lgkmcnt(0)" ::: "memory");
    __builtin_amdgcn_sched_barrier(0);
    __builtin_amdgcn_s_barrier();
    __builtin_amdgcn_sched_barrier(0);

    // ---------------- pipelined tile loop ----------------
    #pragma unroll
    for (int t = 0; t < T_TILES; ++t) {
        const int cur = t & 1;
        uint32_t grn[16];
        float    qn = 0.f;

        // ---- ISSUE tile t+1: x loads first, then idx->gathers, then q ----
        if (t + 1 < T_TILES) {
            const int p0 = (blockIdx.x + (t + 1) * GRID_ATT) * 4;
            const int b = p0 >> 14, n0 = p0 & 16383, p = p0 + wv;
            const float* xbase = xinfo + (((size_t)b * 64) * NPT + n0) * 16;
            #pragma unroll
            for (int i = 0; i < 4; ++i) {
                int f = tid + i * 256, c = f >> 4, s = f & 15;
                xr[i] = __builtin_nontemporal_load(
                    reinterpret_cast<const f32x4*>(xbase + (size_t)c * (NPT * 16) + s * 4));
            }
            const int pu = __builtin_amdgcn_readfirstlane(p);
            const int4* ir = reinterpret_cast<const int4*>(nidx + ((size_t)pu << 4));
            int4 a0 = ir[0], a1 = ir[1], a2 = ir[2], a3 = ir[3];
            const int idxs[16] = {a0.x,a0.y,a0.z,a0.w, a1.x,a1.y,a1.z,a1.w,
                                  a2.x,a2.y,a2.z,a2.w, a3.x,a3.y,a3.z,a3.w};
            #pragma unroll
            for (int j = 0; j < 16; ++j)
                grn[j] = kv[(((size_t)((b << 14) | idxs[j])) << 6) + lane];
            qn = bf16_lo((uint32_t)__builtin_nontemporal_load(
                     qfeat + ((size_t)p << 6) + lane));
        }

        // ---- COMPUTE tile t (gr/qc loaded an iteration ago; xs[cur] ready) ----
        {
            const int p = (blockIdx.x + t * GRID_ATT) * 4 + wv;
            float es = 0.f, fsum = 0.f;
            #pragma unroll
            for (int k4 = 0; k4 < 4; ++k4) {
                float4 x4 = *reinterpret_cast<const float4*>(&xs[cur][lane][wv * 16 + k4 * 4]);
                float xv[4] = {x4.x, x4.y, x4.z, x4.w};
                #pragma unroll
                for (int q4 = 0; q4 < 4; ++q4) {
                    int j = k4 * 4 + q4;
                    float e = __expf(xv[q4] * (bf16_hi(gr[j]) - qc));
                    es += e;
                    fsum = fmaf(e, bf16_lo(gr[j]), fsum);
                }
            }
            qfeat[((size_t)p << 6) + lane] = (uint16_t)bf16_rtne(fsum / es);
        }

        // ---- STAGE tile t+1's x into xs[cur^1]; rotate; raw barrier ----
        if (t + 1 < T_TILES) {
            #pragma unroll
            for (int i = 0; i < 4; ++i) {
                int f = tid + i * 256, c = f >> 4, s = f & 15;
                *reinterpret_cast<f32x4*>(&xs[cur ^ 1][c][s * 4]) = xr[i];
            }
            #pragma unroll
            for (int j = 0; j < 16; ++j) gr[j] = grn[j];
            qc = qn;
            asm volatile("s_waitcnt lgkmcnt(0)" ::: "memory");
            __builtin_amdgcn_sched_barrier(0);
            __builtin_amdgcn_s_barrier();
            __builtin_amdgcn_sched_barrier(0);
        }
    }
}

// ---------------------------------------------------------------------------
// K3: mlp2 = 1x1 conv (O=128) + BN(eps=1e-6) + LeakyReLU(0.2). (unchanged r9)
// ---------------------------------------------------------------------------
__global__ __launch_bounds__(256) void k_mlp2(
    const uint16_t* __restrict__ feat,
    const float* __restrict__ m2w,
    const float* __restrict__ g2, const float* __restrict__ b2,
    const float* __restrict__ m2, const float* __restrict__ v2,
    float* __restrict__ out)
{
    __shared__ float wt [64][132];
    __shared__ float fsh[64][69];
    const int tid = threadIdx.x;
    const int b   = blockIdx.y;
    const int n0  = blockIdx.x * 64;

    {
        const int o  = tid >> 1;
        const int ch = (tid & 1) * 32;
        const float4* src = reinterpret_cast<const float4*>(m2w + o * 64 + ch);
        #pragma unroll
        for (int k4 = 0; k4 < 8; ++k4) {
            float4 w4 = src[k4];
            wt[ch + k4 * 4 + 0][o] = w4.x;
            wt[ch + k4 * 4 + 1][o] = w4.y;
            wt[ch + k4 * 4 + 2][o] = w4.z;
            wt[ch + k4 * 4 + 3][o] = w4.w;
        }
    }
    {
        const int c8 = tid & 7;
        const int nl = tid >> 3;
        #pragma unroll
        for (int half = 0; half < 2; ++half) {
            int n = nl + half * 32;
            u32x4 rw = *reinterpret_cast<const u32x4*>(
                feat + (((size_t)b * NPT + n0 + n) << 6) + c8 * 8);
            #pragma unroll
            for (int k = 0; k < 4; ++k) {
                uint32_t w2 = rw[k];
                fsh[c8 * 8 + k * 2 + 0][n] = bf16_lo(w2);
                fsh[c8 * 8 + k * 2 + 1][n] = bf16_hi(w2);
            }
        }
    }
    __syncthreads();

    const int tn = tid & 15;
    const int to = tid >> 4;
    float acc[2][4][4];
    #pragma unroll
    for (int h = 0; h < 2; ++h)
        #pragma unroll
        for (int i = 0; i < 4; ++i)
            #pragma unroll
            for (int j = 0; j < 4; ++j) acc[h][i][j] = 0.f;

    #pragma unroll 4
    for (int c = 0; c < 64; ++c) {
        float4 wa = *reinterpret_cast<const float4*>(&wt[c][to * 4]);
        float4 wb = *reinterpret_cast<const float4*>(&wt[c][64 + to * 4]);
        float4 f4 = *reinterpret_cast<const float4*>(&fsh[c][tn * 4]);
        float wra[4] = {wa.x, wa.y, wa.z, wa.w};
        float wrb[4] = {wb.x, wb.y, wb.z, wb.w};
        float fr[4]  = {f4.x, f4.y, f4.z, f4.w};
        #pragma unroll
        for (int oi = 0; oi < 4; ++oi)
            #pragma unroll
            for (int ni = 0; ni < 4; ++ni) {
                acc[0][oi][ni] = fmaf(wra[oi], fr[ni], acc[0][oi][ni]);
                acc[1][oi][ni] = fmaf(wrb[oi], fr[ni], acc[1][oi][ni]);
            }
    }

    #pragma unroll
    for (int h = 0; h < 2; ++h)
        #pragma unroll
        for (int oi = 0; oi < 4; ++oi) {
            int o = h * 64 + to * 4 + oi;
            float s  = g2[o] * rsqrtf(v2[o] + 1e-6f);
            float sh = b2[o] - m2[o] * s;
            f32x4 r;
            #pragma unroll
            for (int ni = 0; ni < 4; ++ni) {
                float y = fmaf(acc[h][oi][ni], s, sh);
                r[ni] = (y >= 0.f) ? y : 0.2f * y;
            }
            __builtin_nontemporal_store(r, reinterpret_cast<f32x4*>(
                out + (((size_t)b << 7) + o) * NPT + n0 + tn * 4));
        }
}

// ---------------------------------------------------------------------------
extern "C" void kernel_launch(void* const* d_in, const int* in_sizes, int n_in,
                              void* d_out, int out_size, void* d_ws, size_t ws_size,
                              hipStream_t stream)
{
    const float* xinfo   = (const float*)d_in[0];
    const float* feature = (const float*)d_in[1];
    const int*   nidx    = (const int*)  d_in[2];
    const float* Wq = (const float*)d_in[3];
    const float* Qg = (const float*)d_in[4];
    const float* Qb = (const float*)d_in[5];
    const float* Qm = (const float*)d_in[6];
    const float* Qv = (const float*)d_in[7];
    const float* Wk = (const float*)d_in[8];
    const float* Kg = (const float*)d_in[9];
    const float* Kb = (const float*)d_in[10];
    const float* Km = (const float*)d_in[11];
    const float* Kv = (const float*)d_in[12];
    const float* Wv = (const float*)d_in[13];
    const float* Vg = (const float*)d_in[14];
    const float* Vb = (const float*)d_in[15];
    const float* Vm = (const float*)d_in[16];
    const float* Vv = (const float*)d_in[17];
    const float* m2w = (const float*)d_in[18];
    const float* g2  = (const float*)d_in[19];
    const float* b2  = (const float*)d_in[20];
    const float* m2  = (const float*)d_in[21];
    const float* v2  = (const float*)d_in[22];
    float* out = (float*)d_out;

    // workspace: q/feat (bf16, in-place) 8 MiB, packed kv 16 MiB
    uint16_t* qf    = (uint16_t*)d_ws;
    uint32_t* kvbuf = (uint32_t*)((uint8_t*)d_ws + (8u << 20));

    k_qkv<<<dim3(NPT / 64, NB), 256, 0, stream>>>(
        feature, Wq, Wk, Wv,
        Qg, Qb, Qm, Qv, Kg, Kb, Km, Kv, Vg, Vb, Vm, Vv,
        qf, kvbuf);

    k_attn<<<GRID_ATT, 256, 0, stream>>>(xinfo, nidx, qf, kvbuf);

    k_mlp2<<<dim3(NPT / 64, NB), 256, 0, stream>>>(qf, m2w, g2, b2, m2, v2, out);
}

// Round 11
// 110.660 us; speedup vs baseline: 1.0972x; 1.0972x over previous
//
#include <hip/hip_runtime.h>
#include <cstddef>
#include <cstdint>

#define NPT 16384   // N
#define NB  4       // B
// C = 64, K = 16, O = 128

typedef float    f32x4 __attribute__((ext_vector_type(4)));
typedef uint32_t u32x4 __attribute__((ext_vector_type(4)));
typedef uint16_t u16x4 __attribute__((ext_vector_type(4)));

__device__ __forceinline__ uint32_t bf16_rtne(float f) {
    uint32_t u = __builtin_bit_cast(uint32_t, f);
    return (u + 0x7FFFu + ((u >> 16) & 1u)) >> 16;
}
__device__ __forceinline__ float bf16_hi(uint32_t w) {   // high 16 bits
    return __builtin_bit_cast(float, w & 0xFFFF0000u);
}
__device__ __forceinline__ float bf16_lo(uint32_t w) {   // low 16 bits
    return __builtin_bit_cast(float, w << 16);
}

// ---------------------------------------------------------------------------
// K1: fused 1x1 conv + BN(eps=1e-5) + ReLU for q, k, v.
// q out: [B][N][64] bf16 (u16). k,v out PACKED bf16: kv[p][c]=(k<<16)|v (u32).
// grid (N/64, B), block 256. Register-tiled GEMM, M=192 (q|k|v), tile n=64.
// ---------------------------------------------------------------------------
__global__ __launch_bounds__(256) void k_qkv(
    const float* __restrict__ feat_in,
    const float* __restrict__ Wq, const float* __restrict__ Wk, const float* __restrict__ Wv,
    const float* __restrict__ Qg, const float* __restrict__ Qb, const float* __restrict__ Qm, const float* __restrict__ Qv,
    const float* __restrict__ Kg, const float* __restrict__ Kb, const float* __restrict__ Km, const float* __restrict__ Kv,
    const float* __restrict__ Vg, const float* __restrict__ Vb, const float* __restrict__ Vm, const float* __restrict__ Vv,
    uint16_t* __restrict__ qo, uint32_t* __restrict__ kvo)
{
    __shared__ float wt[64][192];   // wt[c][t*64+o] = W_t[o][c]   (48 KiB)
    __shared__ float fs[64][64];    // fs[c][n_local]              (16 KiB)
    const int tid = threadIdx.x;
    const int b   = blockIdx.y;
    const int n0  = blockIdx.x * 64;

    // ---- stage weights transposed (unscaled; BN folded in epilogue) ----
    {
        const int o  = tid >> 2;          // 0..63
        const int cb = (tid & 3) * 16;    // 0,16,32,48
        const float* Ws[3] = {Wq, Wk, Wv};
        #pragma unroll
        for (int t = 0; t < 3; ++t) {
            const float4* src = reinterpret_cast<const float4*>(Ws[t] + o * 64 + cb);
            #pragma unroll
            for (int k4 = 0; k4 < 4; ++k4) {
                float4 w4 = src[k4];
                wt[cb + k4 * 4 + 0][t * 64 + o] = w4.x;
                wt[cb + k4 * 4 + 1][t * 64 + o] = w4.y;
                wt[cb + k4 * 4 + 2][t * 64 + o] = w4.z;
                wt[cb + k4 * 4 + 3][t * 64 + o] = w4.w;
            }
        }
    }
    // ---- stage feature tile: fs[c][n] from feature[b][c][n0+n] ----
    #pragma unroll
    for (int i = 0; i < 16; ++i) {
        int flat = tid + i * 256;       // 4096 elements
        int c = flat >> 6, n = flat & 63;
        fs[c][n] = feat_in[((size_t)b * 64 + c) * NPT + n0 + n];
    }
    __syncthreads();

    const int to = tid & 15;   // o-quad
    const int tn = tid >> 4;   // n-quad
    float acc[3][4][4];
    #pragma unroll
    for (int t = 0; t < 3; ++t)
        #pragma unroll
        for (int i = 0; i < 4; ++i)
            #pragma unroll
            for (int j = 0; j < 4; ++j) acc[t][i][j] = 0.f;

    #pragma unroll 4
    for (int c = 0; c < 64; ++c) {
        float4 f4  = *reinterpret_cast<const float4*>(&fs[c][tn * 4]);
        float4 wq4 = *reinterpret_cast<const float4*>(&wt[c][to * 4]);
        float4 wk4 = *reinterpret_cast<const float4*>(&wt[c][64 + to * 4]);
        float4 wv4 = *reinterpret_cast<const float4*>(&wt[c][128 + to * 4]);
        float fr[4]    = {f4.x, f4.y, f4.z, f4.w};
        float wr[3][4] = {{wq4.x, wq4.y, wq4.z, wq4.w},
                          {wk4.x, wk4.y, wk4.z, wk4.w},
                          {wv4.x, wv4.y, wv4.z, wv4.w}};
        #pragma unroll
        for (int t = 0; t < 3; ++t)
            #pragma unroll
            for (int oi = 0; oi < 4; ++oi)
                #pragma unroll
                for (int nn = 0; nn < 4; ++nn)
                    acc[t][oi][nn] = fmaf(wr[t][oi], fr[nn], acc[t][oi][nn]);
    }

    // ---- epilogue: BN fold + ReLU; q -> bf16, k,v -> packed bf16x2 ----
    float scq[4], shq[4], sck[4], shk[4], scv[4], shv[4];
    #pragma unroll
    for (int oi = 0; oi < 4; ++oi) {
        int o = to * 4 + oi;
        float s;
        s = Qg[o] * rsqrtf(Qv[o] + 1e-5f); scq[oi] = s; shq[oi] = Qb[o] - Qm[o] * s;
        s = Kg[o] * rsqrtf(Kv[o] + 1e-5f); sck[oi] = s; shk[oi] = Kb[o] - Km[o] * s;
        s = Vg[o] * rsqrtf(Vv[o] + 1e-5f); scv[oi] = s; shv[oi] = Vb[o] - Vm[o] * s;
    }
    #pragma unroll
    for (int nn = 0; nn < 4; ++nn) {
        const size_t pidx = (size_t)b * NPT + n0 + tn * 4 + nn;
        u16x4 rq;
        u32x4 pk;
        #pragma unroll
        for (int oi = 0; oi < 4; ++oi) {
            float q = fmaxf(fmaf(acc[0][oi][nn], scq[oi], shq[oi]), 0.f);
            float rk = fmaxf(fmaf(acc[1][oi][nn], sck[oi], shk[oi]), 0.f);
            float rv = fmaxf(fmaf(acc[2][oi][nn], scv[oi], shv[oi]), 0.f);
            rq[oi] = (uint16_t)bf16_rtne(q);
            pk[oi] = (bf16_rtne(rk) << 16) | bf16_rtne(rv);
        }
        *reinterpret_cast<u16x4*>(qo  + (pidx << 6) + to * 4) = rq;
        *reinterpret_cast<u32x4*>(kvo + (pidx << 6) + to * 4) = pk;
    }
}

// ---------------------------------------------------------------------------
// K2: gather + attention + weighted sum. One wave per point, lane = channel.
// (r5-best config: 4 points / 256-thread block.) Scalar idx path; bf16x2 kv
// gathers (L2-resident); x_info streamed non-temporal through LDS tile.
// q read bf16; feat written bf16 over q IN PLACE. Softmax without max-sub
// (|w| <= ~6, overflow-safe; shorter dependency chain).
// ---------------------------------------------------------------------------
__global__ __launch_bounds__(256) void k_attn(
    const float*    __restrict__ xinfo,
    const int*      __restrict__ nidx,
    uint16_t*                    qfeat,   // q in (bf16), feat out (bf16)
    const uint32_t* __restrict__ kv)
{
    __shared__ float xs[64][68];   // [c][pl*16+j], pad 4 -> <=2-way bank alias
    const int tid  = threadIdx.x;
    const int lane = tid & 63;
    const int wv   = tid >> 6;
    const int p0   = blockIdx.x * 4;
    const int b    = p0 >> 14;
    const int n0   = p0 & 16383;
    const int p    = p0 + wv;

    // ---- neighbor indices via SCALAR path (p is wave-uniform) ----
    const int pu = __builtin_amdgcn_readfirstlane(p);
    const int4* irow = reinterpret_cast<const int4*>(nidx + ((size_t)pu << 4));
    int4 i0 = irow[0], i1 = irow[1], i2 = irow[2], i3 = irow[3];
    const int idxs[16] = {i0.x, i0.y, i0.z, i0.w,  i1.x, i1.y, i1.z, i1.w,
                          i2.x, i2.y, i2.z, i2.w,  i3.x, i3.y, i3.z, i3.w};

    // ---- gathers first: 16 independent loads, SGPR base + lane*4 ----
    uint32_t gr[16];
    #pragma unroll
    for (int j = 0; j < 16; ++j)
        gr[j] = kv[(((size_t)((b << 14) | idxs[j])) << 6) + lane];

    uint16_t qraw = __builtin_nontemporal_load(qfeat + ((size_t)p << 6) + lane);
    float qc = bf16_lo((uint32_t)qraw);

    // ---- cooperative x_info tile load (nt): 4096 floats = 4 x f32x4/thread ----
    const float* xbase = xinfo + (((size_t)b * 64) * NPT + n0) * 16;
    f32x4 xr[4];
    #pragma unroll
    for (int i = 0; i < 4; ++i) {
        int f = tid + i * 256;        // float4 index in tile, 0..1023
        int c = f >> 4, s = f & 15;   // channel, 16B-segment within 256B run
        xr[i] = __builtin_nontemporal_load(
            reinterpret_cast<const f32x4*>(xbase + (size_t)c * (NPT * 16) + s * 4));
    }
    #pragma unroll
    for (int i = 0; i < 4; ++i) {
        int f = tid + i * 256;
        int c = f >> 4, s = f & 15;
        *reinterpret_cast<f32x4*>(&xs[c][s * 4]) = xr[i];
    }
    __syncthreads();

    // ---- softmax over K=16, fully in-lane, no max-sub ----
    float es = 0.f, fsum = 0.f;
    #pragma unroll
    for (int k4 = 0; k4 < 4; ++k4) {
        float4 x4 = *reinterpret_cast<const float4*>(&xs[lane][wv * 16 + k4 * 4]);
        float xv[4] = {x4.x, x4.y, x4.z, x4.w};
        #pragma unroll
        for (int q4 = 0; q4 < 4; ++q4) {
            int j = k4 * 4 + q4;
            float e = __expf(xv[q4] * (bf16_hi(gr[j]) - qc));
            es += e;
            fsum = fmaf(e, bf16_lo(gr[j]), fsum);
        }
    }

    qfeat[((size_t)p << 6) + lane] = (uint16_t)bf16_rtne(fsum / es);
}

// ---------------------------------------------------------------------------
// K3: mlp2 = 1x1 conv (O=128) + BN(eps=1e-6) + LeakyReLU(0.2).
// feat input is bf16 [p][c]; unpacked to fp32 LDS during staging.
// grid (N/64, B), block 256. Tile 128o x 64n. Output [B][128][N]; float4 NT
// stores (256B per 16-lane segment).
// ---------------------------------------------------------------------------
__global__ __launch_bounds__(256) void k_mlp2(
    const uint16_t* __restrict__ feat,
    const float* __restrict__ m2w,
    const float* __restrict__ g2, const float* __restrict__ b2,
    const float* __restrict__ m2, const float* __restrict__ v2,
    float* __restrict__ out)
{
    __shared__ float wt [64][132];  // wt[c][o], padded (33 KiB)
    __shared__ float fsh[64][69];   // fsh[c][n], pad 5 -> 2-way staging writes
    const int tid = threadIdx.x;
    const int b   = blockIdx.y;
    const int n0  = blockIdx.x * 64;

    // ---- stage wt[c][o] from m2w[o][c] ----
    {
        const int o  = tid >> 1;          // 0..127
        const int ch = (tid & 1) * 32;    // 0 or 32
        const float4* src = reinterpret_cast<const float4*>(m2w + o * 64 + ch);
        #pragma unroll
        for (int k4 = 0; k4 < 8; ++k4) {
            float4 w4 = src[k4];
            wt[ch + k4 * 4 + 0][o] = w4.x;
            wt[ch + k4 * 4 + 1][o] = w4.y;
            wt[ch + k4 * 4 + 2][o] = w4.z;
            wt[ch + k4 * 4 + 3][o] = w4.w;
        }
    }
    // ---- stage fsh[c][n] from bf16 feat[b][n0+n][c] ----
    {
        const int c8 = tid & 7;        // channel-octet: c = c8*8 .. +7
        const int nl = tid >> 3;       // 0..31
        #pragma unroll
        for (int half = 0; half < 2; ++half) {
            int n = nl + half * 32;
            u32x4 rw = *reinterpret_cast<const u32x4*>(
                feat + (((size_t)b * NPT + n0 + n) << 6) + c8 * 8);
            #pragma unroll
            for (int k = 0; k < 4; ++k) {
                uint32_t w2 = rw[k];
                fsh[c8 * 8 + k * 2 + 0][n] = bf16_lo(w2);
                fsh[c8 * 8 + k * 2 + 1][n] = bf16_hi(w2);
            }
        }
    }
    __syncthreads();

    const int tn = tid & 15;   // lane's n-quad: n = tn*4 .. tn*4+3 (float4 stores)
    const int to = tid >> 4;   // 0..15 -> o quads {to*4..+3} and {64+to*4..+3}
    float acc[2][4][4];        // [half][oi][ni]
    #pragma unroll
    for (int h = 0; h < 2; ++h)
        #pragma unroll
        for (int i = 0; i < 4; ++i)
            #pragma unroll
            for (int j = 0; j < 4; ++j) acc[h][i][j] = 0.f;

    #pragma unroll 4
    for (int c = 0; c < 64; ++c) {
        float4 wa = *reinterpret_cast<const float4*>(&wt[c][to * 4]);
        float4 wb = *reinterpret_cast<const float4*>(&wt[c][64 + to * 4]);
        float4 f4 = *reinterpret_cast<const float4*>(&fsh[c][tn * 4]);
        float wra[4] = {wa.x, wa.y, wa.z, wa.w};
        float wrb[4] = {wb.x, wb.y, wb.z, wb.w};
        float fr[4]  = {f4.x, f4.y, f4.z, f4.w};
        #pragma unroll
        for (int oi = 0; oi < 4; ++oi)
            #pragma unroll
            for (int ni = 0; ni < 4; ++ni) {
                acc[0][oi][ni] = fmaf(wra[oi], fr[ni], acc[0][oi][ni]);
                acc[1][oi][ni] = fmaf(wrb[oi], fr[ni], acc[1][oi][ni]);
            }
    }

    #pragma unroll
    for (int h = 0; h < 2; ++h)
        #pragma unroll
        for (int oi = 0; oi < 4; ++oi) {
            int o = h * 64 + to * 4 + oi;
            float s  = g2[o] * rsqrtf(v2[o] + 1e-6f);
            float sh = b2[o] - m2[o] * s;
            f32x4 r;
            #pragma unroll
            for (int ni = 0; ni < 4; ++ni) {
                float y = fmaf(acc[h][oi][ni], s, sh);
                r[ni] = (y >= 0.f) ? y : 0.2f * y;
            }
            __builtin_nontemporal_store(r, reinterpret_cast<f32x4*>(
                out + (((size_t)b << 7) + o) * NPT + n0 + tn * 4));
        }
}

// ---------------------------------------------------------------------------
extern "C" void kernel_launch(void* const* d_in, const int* in_sizes, int n_in,
                              void* d_out, int out_size, void* d_ws, size_t ws_size,
                              hipStream_t stream)
{
    const float* xinfo   = (const float*)d_in[0];
    const float* feature = (const float*)d_in[1];
    const int*   nidx    = (const int*)  d_in[2];
    const float* Wq = (const float*)d_in[3];
    const float* Qg = (const float*)d_in[4];
    const float* Qb = (const float*)d_in[5];
    const float* Qm = (const float*)d_in[6];
    const float* Qv = (const float*)d_in[7];
    const float* Wk = (const float*)d_in[8];
    const float* Kg = (const float*)d_in[9];
    const float* Kb = (const float*)d_in[10];
    const float* Km = (const float*)d_in[11];
    const float* Kv = (const float*)d_in[12];
    const float* Wv = (const float*)d_in[13];
    const float* Vg = (const float*)d_in[14];
    const float* Vb = (const float*)d_in[15];
    const float* Vm = (const float*)d_in[16];
    const float* Vv = (const float*)d_in[17];
    const float* m2w = (const float*)d_in[18];
    const float* g2  = (const float*)d_in[19];
    const float* b2  = (const float*)d_in[20];
    const float* m2  = (const float*)d_in[21];
    const float* v2  = (const float*)d_in[22];
    float* out = (float*)d_out;

    // workspace: q/feat (bf16, in-place) 8 MiB, packed kv 16 MiB
    uint16_t* qf    = (uint16_t*)d_ws;
    uint32_t* kvbuf = (uint32_t*)((uint8_t*)d_ws + (8u << 20));

    k_qkv<<<dim3(NPT / 64, NB), 256, 0, stream>>>(
        feature, Wq, Wk, Wv,
        Qg, Qb, Qm, Qv, Kg, Kb, Km, Kv, Vg, Vb, Vm, Vv,
        qf, kvbuf);

    k_attn<<<(NB * NPT) / 4, 256, 0, stream>>>(xinfo, nidx, qf, kvbuf);

    k_mlp2<<<dim3(NPT / 64, NB), 256, 0, stream>>>(qf, m2w, g2, b2, m2, v2, out);
}